// Round 1
// 527.273 us; speedup vs baseline: 1.1367x; 1.1367x over previous
//
#include <hip/hip_runtime.h>

#define M_DIM 8192
#define N_DIM 4096
#define K_DIM 4096
#define BK 32
#define NT (K_DIM / BK)   // 128 K-tiles

typedef __attribute__((ext_vector_type(8))) short bf16x8;
typedef __attribute__((ext_vector_type(8))) unsigned short u16x8;
typedef __attribute__((ext_vector_type(4))) float f32x4;

__device__ inline unsigned short f32_to_bf16_rne(float f) {
  unsigned int u = __float_as_uint(f);
  u += 0x7FFFu + ((u >> 16) & 1u);   // round-to-nearest-even
  return (unsigned short)(u >> 16);
}

// fp32 -> bf16 cast, 8 elements/thread, 16B loads + 16B store
__global__ __launch_bounds__(256) void cvt_f32_bf16_kernel(
    const float* __restrict__ in, unsigned short* __restrict__ out) {
  const int i = (blockIdx.x * 256 + threadIdx.x) * 8;
  float4 v0 = *(const float4*)(in + i);
  float4 v1 = *(const float4*)(in + i + 4);
  u16x8 o;
  o[0] = f32_to_bf16_rne(v0.x);
  o[1] = f32_to_bf16_rne(v0.y);
  o[2] = f32_to_bf16_rne(v0.z);
  o[3] = f32_to_bf16_rne(v0.w);
  o[4] = f32_to_bf16_rne(v1.x);
  o[5] = f32_to_bf16_rne(v1.y);
  o[6] = f32_to_bf16_rne(v1.z);
  o[7] = f32_to_bf16_rne(v1.w);
  *(u16x8*)(out + i) = o;
}

__device__ inline void gld_lds16(const void* g, void* l) {
  __builtin_amdgcn_global_load_lds(
      (__attribute__((address_space(1))) void*)(g),
      (__attribute__((address_space(3))) void*)(l),
      16, 0, 0);
}

// C[m][n] = sum_k A[m][k] * B[n][k]  (gemm_bt), then *scale[n] + bias[n].
//
// 256x256 tile, BK=32, 512 threads = 8 waves (2M x 4N), wave = 128x64 of C.
// 4-deep LDS ring (4 x (A 256x32 + B 256x32) bf16 = 128 KiB): tile t lives in
// buf t&3; during tile t we prefetch tile t+2 into buf (t+2)&3 (free since
// tile t-2 finished two tiles ago). ONE counted s_waitcnt vmcnt(4) per K-tile
// (tile t+1 landed, tile t+2's 4 loads stay in flight across the barrier) --
// never vmcnt(0), no __syncthreads() (which would force a full drain).
// Per K-tile: 2 phases x {ds_reads | stage | barrier | lgkmcnt(0) |
// setprio(1) 16 MFMA setprio(0) | barrier}.
//
// LDS swizzle (both-sides, verified 0 bank conflicts at 128-tile): 16B chunk
// stored at col (origChunk ^ ((row>>1)&3)); global source pre-swizzled so
// global_load_lds' linear dest lands swizzled; ds_read applies same XOR.
__global__ __launch_bounds__(512, 2) void gemm_sign_kernel(
    const unsigned short* __restrict__ A,
    const unsigned short* __restrict__ Bm,
    const float* __restrict__ scale,
    const float* __restrict__ bias,
    float* __restrict__ C) {
  __shared__ __align__(16) unsigned short smA[4][256 * BK];  // 64 KiB
  __shared__ __align__(16) unsigned short smB[4][256 * BK];  // 64 KiB

  const int tid   = threadIdx.x;
  const int lane  = tid & 63;
  const int wave  = tid >> 6;
  const int waveM = wave >> 2;          // 0..1
  const int waveN = wave & 3;           // 0..3
  const int lrow  = lane & 15;

  // T1: XCD-aware bijective swizzle. 512 blocks, 512%8==0.
  // bid%8 = XCD -> each XCD gets 64 consecutive wgids = 4 M-rows x 16 N
  // (consecutive blocks share the 2 MiB A-panel -> L2-resident).
  const int bid   = blockIdx.x;
  const int wgid  = (bid & 7) * 64 + (bid >> 3);
  const int mBase = (wgid >> 4) * 256;  // 32 M-tiles
  const int nBase = (wgid & 15) * 256;  // 16 N-tiles

  // --- staging source (pre-swizzled): LDS dest is linear at chunk index
  // p = loadIdx*512 + tid; (row = p>>2, storedChunk = p&3) holds global chunk
  // storedChunk ^ ((row>>1)&3) = (tid&3) ^ ((tid>>3)&3)  (same for both loads:
  // row+128 keeps (row>>1)&3).
  const int srow = tid >> 2;                              // 0..127
  const int gcol = ((tid & 3) ^ ((tid >> 3) & 3)) * 8;    // swizzled chunk (elems)
  const unsigned short* aSrc = A  + (size_t)(mBase + srow) * K_DIM + gcol;
  const unsigned short* bSrc = Bm + (size_t)(nBase + srow) * K_DIM + gcol;
  const size_t rowStr128 = (size_t)128 * K_DIM;

#define STAGE_A(buf, kt) do {                                        \
    const unsigned short* _s = aSrc + (size_t)(kt) * BK;             \
    gld_lds16(_s,             &smA[buf][tid * 8]);                   \
    gld_lds16(_s + rowStr128, &smA[buf][4096 + tid * 8]);            \
  } while (0)
#define STAGE_B(buf, kt) do {                                        \
    const unsigned short* _s = bSrc + (size_t)(kt) * BK;             \
    gld_lds16(_s,             &smB[buf][tid * 8]);                   \
    gld_lds16(_s + rowStr128, &smB[buf][4096 + tid * 8]);            \
  } while (0)

  // --- fragment-read swizzle: row bases are multiples of 16 so
  // (row>>1)&3 == (lrow>>1)&3; storedChunk = (lane>>4) ^ ((lrow>>1)&3).
  const int cSwz = ((lane >> 4) ^ ((lrow >> 1) & 3)) * 8;  // elems
  int aOff[8], bOff[4];
#pragma unroll
  for (int mi = 0; mi < 8; ++mi)
    aOff[mi] = (waveM * 128 + mi * 16 + lrow) * BK + cSwz;
#pragma unroll
  for (int ni = 0; ni < 4; ++ni)
    bOff[ni] = (waveN * 64 + ni * 16 + lrow) * BK + cSwz;

  f32x4 acc[8][4];
#pragma unroll
  for (int i = 0; i < 8; ++i)
#pragma unroll
    for (int j = 0; j < 4; ++j)
      acc[i][j] = (f32x4){0.f, 0.f, 0.f, 0.f};

  // --- prologue: stage tiles 0,1; wait tile 0 (tile 1's 4 loads stay in flight)
  STAGE_A(0, 0); STAGE_B(0, 0);
  STAGE_A(1, 1); STAGE_B(1, 1);
  asm volatile("s_waitcnt vmcnt(4)" ::: "memory");
  __builtin_amdgcn_s_barrier();

#pragma unroll 4
  for (int t = 0; t < NT; ++t) {
    const int cur = t & 3;
    const int pre = (t + 2) & 3;
    const int kt2 = (t + 2 < NT) ? (t + 2) : (NT - 1);  // clamp: keeps vmcnt
                                                        // bookkeeping uniform
    bf16x8 af[4], bf[4];

    // ---- phase 1: frags a[0..3], b[0..3]; stage A of tile t+2
#pragma unroll
    for (int ni = 0; ni < 4; ++ni)
      bf[ni] = *(const bf16x8*)&smB[cur][bOff[ni]];
#pragma unroll
    for (int mi = 0; mi < 4; ++mi)
      af[mi] = *(const bf16x8*)&smA[cur][aOff[mi]];
    STAGE_A(pre, kt2);
    __builtin_amdgcn_s_barrier();
    asm volatile("s_waitcnt lgkmcnt(0)" ::: "memory");
    __builtin_amdgcn_s_setprio(1);
#pragma unroll
    for (int mi = 0; mi < 4; ++mi)
#pragma unroll
      for (int ni = 0; ni < 4; ++ni)
        acc[mi][ni] = __builtin_amdgcn_mfma_f32_16x16x32_bf16(
            af[mi], bf[ni], acc[mi][ni], 0, 0, 0);
    __builtin_amdgcn_s_setprio(0);
    __builtin_amdgcn_s_barrier();

    // ---- phase 2: frags a[4..7] (b reused); stage B of tile t+2;
    //      counted wait: tile t+1 landed, tile t+2 still flying.
#pragma unroll
    for (int mi = 0; mi < 4; ++mi)
      af[mi] = *(const bf16x8*)&smA[cur][aOff[4 + mi]];
    STAGE_B(pre, kt2);
    asm volatile("s_waitcnt vmcnt(4)" ::: "memory");
    __builtin_amdgcn_s_barrier();
    asm volatile("s_waitcnt lgkmcnt(0)" ::: "memory");
    __builtin_amdgcn_s_setprio(1);
#pragma unroll
    for (int mi = 0; mi < 4; ++mi)
#pragma unroll
      for (int ni = 0; ni < 4; ++ni)
        acc[4 + mi][ni] = __builtin_amdgcn_mfma_f32_16x16x32_bf16(
            af[mi], bf[ni], acc[4 + mi][ni], 0, 0, 0);
    __builtin_amdgcn_s_setprio(0);
    __builtin_amdgcn_s_barrier();
  }
#undef STAGE_A
#undef STAGE_B

  // epilogue: C/D layout col = lane&15, row = (lane>>4)*4 + reg   [m89/m91]
#pragma unroll
  for (int ni = 0; ni < 4; ++ni) {
    const int c = nBase + waveN * 64 + ni * 16 + lrow;
    const float sc = scale[c];
    const float bs = bias[c];
#pragma unroll
    for (int mi = 0; mi < 8; ++mi) {
      const int r0 = mBase + waveM * 128 + mi * 16 + (lane >> 4) * 4;
#pragma unroll
      for (int r = 0; r < 4; ++r)
        C[(size_t)(r0 + r) * N_DIM + c] = acc[mi][ni][r] * sc + bs;
    }
  }
}

extern "C" void kernel_launch(void* const* d_in, const int* in_sizes, int n_in,
                              void* d_out, int out_size, void* d_ws, size_t ws_size,
                              hipStream_t stream) {
  const float* x     = (const float*)d_in[0];  // (B,S,IN) = (4,2048,4096) fp32
  const float* sign  = (const float*)d_in[1];  // (OUT,IN) = (4096,4096) fp32, +/-1
  const float* scale = (const float*)d_in[2];  // (4096,)
  const float* bias  = (const float*)d_in[3];  // (4096,)
  float* out = (float*)d_out;                  // (B,S,OUT) fp32

  unsigned short* xb    = (unsigned short*)d_ws;            // M*K bf16 = 64 MiB
  unsigned short* signb = xb + (size_t)M_DIM * K_DIM;       // N*K bf16 = 32 MiB

  // casts: 8 elems/thread
  cvt_f32_bf16_kernel<<<(M_DIM * K_DIM) / 2048, 256, 0, stream>>>(x, xb);
  cvt_f32_bf16_kernel<<<(N_DIM * K_DIM) / 2048, 256, 0, stream>>>(sign, signb);

  // 256x256 tiles: (8192/256) * (4096/256) = 32 * 16 = 512 blocks, 512 thr
  gemm_sign_kernel<<<dim3(512), dim3(512), 0, stream>>>(xb, signb, scale, bias, out);
}

// Round 2
// 523.772 us; speedup vs baseline: 1.1443x; 1.0067x over previous
//
#include <hip/hip_runtime.h>

#define M_DIM 8192
#define N_DIM 4096
#define K_DIM 4096
#define BK 32
#define NT (K_DIM / BK)   // 128 K-tiles

typedef __attribute__((ext_vector_type(8))) short bf16x8;
typedef __attribute__((ext_vector_type(8))) unsigned short u16x8;
typedef __attribute__((ext_vector_type(4))) float f32x4;

__device__ inline unsigned short f32_to_bf16_rne(float f) {
  unsigned int u = __float_as_uint(f);
  u += 0x7FFFu + ((u >> 16) & 1u);   // round-to-nearest-even
  return (unsigned short)(u >> 16);
}

// fp32 -> bf16 cast, 8 elements/thread, 16B loads + 16B store
__global__ __launch_bounds__(256) void cvt_f32_bf16_kernel(
    const float* __restrict__ in, unsigned short* __restrict__ out) {
  const int i = (blockIdx.x * 256 + threadIdx.x) * 8;
  float4 v0 = *(const float4*)(in + i);
  float4 v1 = *(const float4*)(in + i + 4);
  u16x8 o;
  o[0] = f32_to_bf16_rne(v0.x);
  o[1] = f32_to_bf16_rne(v0.y);
  o[2] = f32_to_bf16_rne(v0.z);
  o[3] = f32_to_bf16_rne(v0.w);
  o[4] = f32_to_bf16_rne(v1.x);
  o[5] = f32_to_bf16_rne(v1.y);
  o[6] = f32_to_bf16_rne(v1.z);
  o[7] = f32_to_bf16_rne(v1.w);
  *(u16x8*)(out + i) = o;
}

__device__ inline void gld_lds16(const void* g, void* l) {
  __builtin_amdgcn_global_load_lds(
      (__attribute__((address_space(1))) void*)(g),
      (__attribute__((address_space(3))) void*)(l),
      16, 0, 0);
}

// C[m][n] = sum_k A[m][k] * B[n][k]  (gemm_bt), then *scale[n] + bias[n].
//
// 256x256 tile, BK=32, 512 threads = 8 waves (2M x 4N), wave = 128x64 of C.
// 4-deep LDS ring (128 KiB). Software-pipelined at BOTH levels:
//   global->LDS : stage tile t+3 during tile t; one counted vmcnt(4)/tile
//                 (t+2 landed, t+3's 4 loads stay in flight). Never vmcnt(0).
//   LDS->regs   : fragment double-buffer. Phase 1 of tile t issues reads for
//                 phase 2's A-frags (afQ) then MFMAs with frags read LAST
//                 phase; phase 2 issues reads for tile t+1's frags (bfN+afP,
//                 ring buffer already landed) then MFMAs phase 2. Counted
//                 lgkmcnt(4)/(8) -- reads stay in flight under the MFMAs.
// 2 raw s_barriers per K-tile; no __syncthreads (would drain vmcnt to 0).
//
// Hazards (verified chain): reads of ring buf b complete before the wave's
// MFMA that consumes them (counted lgkm wait), so by the following barrier
// ALL waves are done reading buf b; staging into buf b happens >= 2 tiles
// later, always after that barrier. Reads of tile t+1 during tile t are safe
// because iter t-1 ended with vmcnt(4) (=> t+1 landed) + barrier.
//
// LDS swizzle (both-sides): chunk stored at col (origChunk ^ ((row>>1)&3));
// global source pre-swizzled so global_load_lds' linear dest lands swizzled;
// ds_read applies the same XOR. (0 bank conflicts measured.)
__global__ __launch_bounds__(512, 2) void gemm_sign_kernel(
    const unsigned short* __restrict__ A,
    const unsigned short* __restrict__ Bm,
    const float* __restrict__ scale,
    const float* __restrict__ bias,
    float* __restrict__ C) {
  __shared__ __align__(16) unsigned short smA[4][256 * BK];  // 64 KiB
  __shared__ __align__(16) unsigned short smB[4][256 * BK];  // 64 KiB

  const int tid   = threadIdx.x;
  const int lane  = tid & 63;
  const int wave  = tid >> 6;
  const int waveM = wave >> 2;          // 0..1
  const int waveN = wave & 3;           // 0..3
  const int lrow  = lane & 15;

  // T1: XCD-aware bijective swizzle (512 blocks, 512%8==0).
  const int bid   = blockIdx.x;
  const int wgid  = (bid & 7) * 64 + (bid >> 3);
  const int mBase = (wgid >> 4) * 256;  // 32 M-tiles
  const int nBase = (wgid & 15) * 256;  // 16 N-tiles

  // staging source (pre-swizzled; see header comment)
  const int srow = tid >> 2;                              // 0..127
  const int gcol = ((tid & 3) ^ ((tid >> 3) & 3)) * 8;    // swizzled chunk
  const unsigned short* aSrc = A  + (size_t)(mBase + srow) * K_DIM + gcol;
  const unsigned short* bSrc = Bm + (size_t)(nBase + srow) * K_DIM + gcol;
  const size_t rowStr128 = (size_t)128 * K_DIM;

#define STAGE_A(buf, kt) do {                                        \
    const unsigned short* _s = aSrc + (size_t)(kt) * BK;             \
    gld_lds16(_s,             &smA[buf][tid * 8]);                   \
    gld_lds16(_s + rowStr128, &smA[buf][4096 + tid * 8]);            \
  } while (0)
#define STAGE_B(buf, kt) do {                                        \
    const unsigned short* _s = bSrc + (size_t)(kt) * BK;             \
    gld_lds16(_s,             &smB[buf][tid * 8]);                   \
    gld_lds16(_s + rowStr128, &smB[buf][4096 + tid * 8]);            \
  } while (0)

  // fragment-read swizzle: row bases multiple of 16 => phase = (lrow>>1)&3
  const int cSwz = ((lane >> 4) ^ ((lrow >> 1) & 3)) * 8;  // elems
  int aOff[8], bOff[4];
#pragma unroll
  for (int mi = 0; mi < 8; ++mi)
    aOff[mi] = (waveM * 128 + mi * 16 + lrow) * BK + cSwz;
#pragma unroll
  for (int ni = 0; ni < 4; ++ni)
    bOff[ni] = (waveN * 64 + ni * 16 + lrow) * BK + cSwz;

  f32x4 acc[8][4];
#pragma unroll
  for (int i = 0; i < 8; ++i)
#pragma unroll
    for (int j = 0; j < 4; ++j)
      acc[i][j] = (f32x4){0.f, 0.f, 0.f, 0.f};

  bf16x8 afP[4], afQ[4], bfE[4], bfO[4];

  // --- prologue: stage tiles 0,1,2 (12 loads); tiles 0,1 landed; read tile-0
  // phase-1 frags (8 reads, left in flight into the loop).
  STAGE_A(0, 0); STAGE_B(0, 0);
  STAGE_A(1, 1); STAGE_B(1, 1);
  STAGE_A(2, 2); STAGE_B(2, 2);
  asm volatile("s_waitcnt vmcnt(4)" ::: "memory");
  __builtin_amdgcn_s_barrier();
#pragma unroll
  for (int ni = 0; ni < 4; ++ni)
    bfE[ni] = *(const bf16x8*)&smB[0][bOff[ni]];
#pragma unroll
  for (int mi = 0; mi < 4; ++mi)
    afP[mi] = *(const bf16x8*)&smA[0][aOff[mi]];

  // TILE_BODY(t, bfC, bfN): bfC = tile t's B-frags (already read),
  // bfN gets tile t+1's B-frags. All register arrays statically indexed.
#define TILE_BODY(t, bfC, bfN)                                          \
  {                                                                     \
    const int cur = (t) & 3;                                            \
    const int pre = ((t) + 3) & 3;                                      \
    const int kt3 = ((t) + 3 < NT) ? ((t) + 3) : (NT - 1);              \
    const int ktn = ((t) + 1 < NT) ? ((t) + 1) : (NT - 1);              \
    const int nxt = ktn & 3;                                            \
    /* ph1: issue afQ reads (this tile's a[4..7]); stage A(t+3);  */    \
    /*      MFMA with frags read last phase. lgkmcnt(4) = prev 8 done */\
    _Pragma("unroll")                                                   \
    for (int mi = 0; mi < 4; ++mi)                                      \
      afQ[mi] = *(const bf16x8*)&smA[cur][aOff[4 + mi]];                \
    STAGE_A(pre, kt3);                                                  \
    asm volatile("s_waitcnt lgkmcnt(4)" ::: "memory");                  \
    __builtin_amdgcn_s_setprio(1);                                      \
    _Pragma("unroll")                                                   \
    for (int mi = 0; mi < 4; ++mi)                                      \
      _Pragma("unroll")                                                 \
      for (int ni = 0; ni < 4; ++ni)                                    \
        acc[mi][ni] = __builtin_amdgcn_mfma_f32_16x16x32_bf16(          \
            afP[mi], bfC[ni], acc[mi][ni], 0, 0, 0);                    \
    __builtin_amdgcn_s_setprio(0);                                      \
    __builtin_amdgcn_s_barrier();                                       \
    /* ph2: issue tile t+1 frag reads (ring landed); stage B(t+3); */   \
    /*      lgkmcnt(8) = afQ done, 8 new reads in flight.          */   \
    _Pragma("unroll")                                                   \
    for (int ni = 0; ni < 4; ++ni)                                      \
      bfN[ni] = *(const bf16x8*)&smB[nxt][bOff[ni]];                    \
    _Pragma("unroll")                                                   \
    for (int mi = 0; mi < 4; ++mi)                                      \
      afP[mi] = *(const bf16x8*)&smA[nxt][aOff[mi]];                    \
    STAGE_B(pre, kt3);                                                  \
    asm volatile("s_waitcnt lgkmcnt(8)" ::: "memory");                  \
    __builtin_amdgcn_s_setprio(1);                                      \
    _Pragma("unroll")                                                   \
    for (int mi = 0; mi < 4; ++mi)                                      \
      _Pragma("unroll")                                                 \
      for (int ni = 0; ni < 4; ++ni)                                    \
        acc[4 + mi][ni] = __builtin_amdgcn_mfma_f32_16x16x32_bf16(      \
            afQ[mi], bfC[ni], acc[4 + mi][ni], 0, 0, 0);                \
    __builtin_amdgcn_s_setprio(0);                                      \
    asm volatile("s_waitcnt vmcnt(4)" ::: "memory");                    \
    __builtin_amdgcn_s_barrier();                                       \
  }

  for (int t = 0; t < NT; t += 2) {
    TILE_BODY(t,     bfE, bfO);
    TILE_BODY(t + 1, bfO, bfE);
  }
#undef TILE_BODY
#undef STAGE_A
#undef STAGE_B

  // epilogue: C/D layout col = lane&15, row = (lane>>4)*4 + reg   [m89/m91]
#pragma unroll
  for (int ni = 0; ni < 4; ++ni) {
    const int c = nBase + waveN * 64 + ni * 16 + lrow;
    const float sc = scale[c];
    const float bs = bias[c];
#pragma unroll
    for (int mi = 0; mi < 8; ++mi) {
      const int r0 = mBase + waveM * 128 + mi * 16 + (lane >> 4) * 4;
#pragma unroll
      for (int r = 0; r < 4; ++r)
        C[(size_t)(r0 + r) * N_DIM + c] = acc[mi][ni][r] * sc + bs;
    }
  }
}

extern "C" void kernel_launch(void* const* d_in, const int* in_sizes, int n_in,
                              void* d_out, int out_size, void* d_ws, size_t ws_size,
                              hipStream_t stream) {
  const float* x     = (const float*)d_in[0];  // (B,S,IN) = (4,2048,4096) fp32
  const float* sign  = (const float*)d_in[1];  // (OUT,IN) = (4096,4096) fp32, +/-1
  const float* scale = (const float*)d_in[2];  // (4096,)
  const float* bias  = (const float*)d_in[3];  // (4096,)
  float* out = (float*)d_out;                  // (B,S,OUT) fp32

  unsigned short* xb    = (unsigned short*)d_ws;            // M*K bf16 = 64 MiB
  unsigned short* signb = xb + (size_t)M_DIM * K_DIM;       // N*K bf16 = 32 MiB

  // casts: 8 elems/thread
  cvt_f32_bf16_kernel<<<(M_DIM * K_DIM) / 2048, 256, 0, stream>>>(x, xb);
  cvt_f32_bf16_kernel<<<(N_DIM * K_DIM) / 2048, 256, 0, stream>>>(sign, signb);

  // 256x256 tiles: (8192/256) * (4096/256) = 32 * 16 = 512 blocks, 512 thr
  gemm_sign_kernel<<<dim3(512), dim3(512), 0, stream>>>(xb, signb, scale, bias, out);
}

// Round 4
// 515.936 us; speedup vs baseline: 1.1616x; 1.0152x over previous
//
#include <hip/hip_runtime.h>

#define M_DIM 8192
#define N_DIM 4096
#define K_DIM 4096
#define BK 32
#define NT 128   // K_DIM / BK

typedef __attribute__((ext_vector_type(8))) short bf16x8;
typedef __attribute__((ext_vector_type(8))) unsigned short u16x8;
typedef __attribute__((ext_vector_type(16))) float f32x16;

__device__ inline unsigned short f32_to_bf16_rne(float f) {
  unsigned int u = __float_as_uint(f);
  u += 0x7FFFu + ((u >> 16) & 1u);   // round-to-nearest-even
  return (unsigned short)(u >> 16);
}

// fp32 -> bf16 cast, 8 elements/thread, 16B loads + 16B store
__global__ __launch_bounds__(256) void cvt_f32_bf16_kernel(
    const float* __restrict__ in, unsigned short* __restrict__ out) {
  const int i = (blockIdx.x * 256 + threadIdx.x) * 8;
  float4 v0 = *(const float4*)(in + i);
  float4 v1 = *(const float4*)(in + i + 4);
  u16x8 o;
  o[0] = f32_to_bf16_rne(v0.x);
  o[1] = f32_to_bf16_rne(v0.y);
  o[2] = f32_to_bf16_rne(v0.z);
  o[3] = f32_to_bf16_rne(v0.w);
  o[4] = f32_to_bf16_rne(v1.x);
  o[5] = f32_to_bf16_rne(v1.y);
  o[6] = f32_to_bf16_rne(v1.z);
  o[7] = f32_to_bf16_rne(v1.w);
  *(u16x8*)(out + i) = o;
}

// global->LDS 16B DMA, offset ALWAYS 0 (proven form; round-3's literal
// offset arg produced NaN = displaced staging -> unstaged-LDS reads).
__device__ inline void gld_lds16(const void* g, void* l) {
  __builtin_amdgcn_global_load_lds(
      (const __attribute__((address_space(1))) void*)(g),
      (__attribute__((address_space(3))) void*)(l), 16, 0, 0);
}

// C[m][n] = sum_k A[m][k] * B[n][k]  (gemm_bt), then *scale[n] + bias[n].
//
// 256x256 tile, BK=32, 512 threads = 8 waves (2M x 4N), wave = 128x64 of C.
// MFMA: 32x32x16 (ceiling 2495 TF vs 2075 for 16x16x32, m119/m06).
//   A/B frag: row = lane&31, k = (lane>>5)*8 + j.  (Any k-permutation error
//   cancels between A and B -- both use the same chunk map -- so numerics do
//   not depend on this assumption; only the row map and the m74/m101-verified
//   C/D layout matter.)
//
// 4-deep LDS ring, flat 128 KiB: A bufs at 0..64K, B at 64K..128K.
// One phase per K-tile: [12 ds_read_b128 | 4 global_load_lds (tile t+3) |
// vmcnt(4) | s_barrier | lgkmcnt(0) | setprio(1) 16 MFMA setprio(0) |
// s_barrier].  vmcnt(4) => tile t+2 landed, t+3's 4 loads stay in flight
// across the barrier (never vmcnt(0) in the main loop).
// Static structure via 4-body unroll: buf indices compile-time, every
// ds_read = base VGPR + imm offset; per-tile VALU = 4 adds (ptr bump).
//
// LDS swizzle (both-sides): 16B chunk of row r stored at chunk ^ p(r),
// p(r) = ((r>>1)&3) ^ ((r>>3)&3); 32-lane b128 reads hit banks balanced.
// global_load_lds writes linearly, so the SOURCE is pre-swizzled (rule #21).
__global__ __launch_bounds__(512, 2) void gemm_sign_kernel(
    const unsigned short* __restrict__ A,
    const unsigned short* __restrict__ Bm,
    const float* __restrict__ scale,
    const float* __restrict__ bias,
    float* __restrict__ C) {
  __shared__ __align__(16) unsigned char sm[131072];  // 128 KiB

  const int tid   = threadIdx.x;
  const int lane  = tid & 63;
  const int wave  = tid >> 6;
  const int waveM = wave >> 2;          // 0..1
  const int waveN = wave & 3;           // 0..3
  const int l31   = lane & 31;
  const int hi    = lane >> 5;          // k-half selector

  // T1: XCD-aware bijective swizzle (512 blocks, 512%8==0).
  const int bid   = blockIdx.x;
  const int wgid  = (bid & 7) * 64 + (bid >> 3);
  const int mBase = (wgid >> 4) * 256;  // 32 M-tiles
  const int nBase = (wgid & 15) * 256;  // 16 N-tiles

  // staging source (pre-swizzled): LDS slot tid -> row=tid>>2, chunk=tid&3;
  // origChunk = (tid&3) ^ p(row), p(row) = ((tid>>3)&3) ^ ((tid>>5)&3).
  // Rows +128 keep p.
  const int srow = tid >> 2;                                         // 0..127
  const int gcol = ((tid & 3) ^ ((tid >> 3) & 3) ^ ((tid >> 5) & 3)) * 8;
  const unsigned short* aP = A  + (size_t)(mBase + srow) * K_DIM + gcol;
  const unsigned short* bP = Bm + (size_t)(nBase + srow) * K_DIM + gcol;
  const size_t rowStr128 = (size_t)128 * K_DIM;

  // Stage ONE K-tile (4 gloads) at current aP/bP, then advance to next tile.
#define STAGE(SBUF) do {                                                \
    gld_lds16(aP,             sm + (SBUF)*16384 + tid*16);              \
    gld_lds16(aP + rowStr128, sm + (SBUF)*16384 + 8192 + tid*16);       \
    gld_lds16(bP,             sm + 65536 + (SBUF)*16384 + tid*16);      \
    gld_lds16(bP + rowStr128, sm + 65536 + (SBUF)*16384 + 8192 + tid*16); \
    aP += BK; bP += BK;                                                 \
  } while (0)

  // read bases (per-lane, bytes): row bases are multiples of 32 => p depends
  // only on l31; chunk = (kk*2+hi) ^ p.
  const int p = ((l31 >> 1) & 3) ^ ((l31 >> 3) & 3);
  const unsigned char* aRd0 = &sm[(waveM * 128 + l31) * 64 + ((hi ^ p) * 16)];
  const unsigned char* aRd1 = &sm[(waveM * 128 + l31) * 64 + (((2 + hi) ^ p) * 16)];
  const unsigned char* bRd0 = &sm[65536 + (waveN * 64 + l31) * 64 + ((hi ^ p) * 16)];
  const unsigned char* bRd1 = &sm[65536 + (waveN * 64 + l31) * 64 + (((2 + hi) ^ p) * 16)];

  f32x16 acc[4][2];
#pragma unroll
  for (int i = 0; i < 4; ++i)
#pragma unroll
    for (int j = 0; j < 2; ++j)
#pragma unroll
      for (int r = 0; r < 16; ++r)
        acc[i][j][r] = 0.f;

  // BODY(BUF, DO_STAGE, SBUF, VMODE): compute ring buf BUF; optionally stage
  // next tile into SBUF. VMODE: 0 none, 1 vmcnt(4), 2 vmcnt(0) (tail only).
#define BODY(BUF, DO_STAGE, SBUF, VMODE)                                \
  {                                                                     \
    bf16x8 af[4][2], bf[2][2];                                          \
    _Pragma("unroll")                                                   \
    for (int mi = 0; mi < 4; ++mi) {                                    \
      af[mi][0] = *(const bf16x8*)(aRd0 + (BUF) * 16384 + mi * 2048);   \
      af[mi][1] = *(const bf16x8*)(aRd1 + (BUF) * 16384 + mi * 2048);   \
    }                                                                   \
    _Pragma("unroll")                                                   \
    for (int ni = 0; ni < 2; ++ni) {                                    \
      bf[ni][0] = *(const bf16x8*)(bRd0 + (BUF) * 16384 + ni * 2048);   \
      bf[ni][1] = *(const bf16x8*)(bRd1 + (BUF) * 16384 + ni * 2048);   \
    }                                                                   \
    if (DO_STAGE) STAGE(SBUF);                                          \
    if ((VMODE) == 1) asm volatile("s_waitcnt vmcnt(4)" ::: "memory");  \
    if ((VMODE) == 2) asm volatile("s_waitcnt vmcnt(0)" ::: "memory");  \
    __builtin_amdgcn_s_barrier();                                       \
    asm volatile("s_waitcnt lgkmcnt(0)" ::: "memory");                  \
    __builtin_amdgcn_s_setprio(1);                                      \
    _Pragma("unroll")                                                   \
    for (int mi = 0; mi < 4; ++mi)                                      \
      _Pragma("unroll")                                                 \
      for (int ni = 0; ni < 2; ++ni) {                                  \
        acc[mi][ni] = __builtin_amdgcn_mfma_f32_32x32x16_bf16(          \
            af[mi][0], bf[ni][0], acc[mi][ni], 0, 0, 0);                \
        acc[mi][ni] = __builtin_amdgcn_mfma_f32_32x32x16_bf16(          \
            af[mi][1], bf[ni][1], acc[mi][ni], 0, 0, 0);                \
      }                                                                 \
    __builtin_amdgcn_s_setprio(0);                                      \
    __builtin_amdgcn_s_barrier();                                       \
  }

  // prologue: stage tiles 0,1,2; vmcnt(4) => tiles 0,1 landed, tile 2 flying;
  // barrier publishes all waves' staging before first reads.
  STAGE(0); STAGE(1); STAGE(2);   // aP/bP now at tile 3
  asm volatile("s_waitcnt vmcnt(4)" ::: "memory");
  __builtin_amdgcn_s_barrier();

  // main loop: 31 iters x 4 tiles = tiles 0..123, staging tiles 3..126.
  // Landing chain: tile staged in body i is vmcnt(4)-guaranteed 2 bodies
  // later and consumed 3 bodies later (after a barrier). Buf overwrite is
  // issued only after the end-barrier of the body that last read it.
  for (int it = 0; it < 31; ++it) {
    BODY(0, 1, 3, 1);
    BODY(1, 1, 0, 1);
    BODY(2, 1, 1, 1);
    BODY(3, 1, 2, 1);
  }

  // tail: tiles 124..127. 124 stages tile 127 (aP at 127); vmcnt(4)=>126
  // landed; 125: vmcnt(0)=>127 landed; 126,127: no waits needed.
  BODY(0, 1, 3, 1);
  BODY(1, 0, 0, 2);
  BODY(2, 0, 0, 0);
  BODY(3, 0, 0, 0);

#undef BODY
#undef STAGE

  // epilogue: 32x32 C/D layout: col = lane&31, row = (reg&3)+8*(reg>>2)+4*hi
#pragma unroll
  for (int ni = 0; ni < 2; ++ni) {
    const int c = nBase + waveN * 64 + ni * 32 + l31;
    const float sc = scale[c];
    const float bs = bias[c];
#pragma unroll
    for (int mi = 0; mi < 4; ++mi) {
      const int r0 = mBase + waveM * 128 + mi * 32 + 4 * hi;
#pragma unroll
      for (int r = 0; r < 16; ++r) {
        const int row = r0 + (r & 3) + 8 * (r >> 2);
        C[(size_t)row * N_DIM + c] = acc[mi][ni][r] * sc + bs;
      }
    }
  }
}

extern "C" void kernel_launch(void* const* d_in, const int* in_sizes, int n_in,
                              void* d_out, int out_size, void* d_ws, size_t ws_size,
                              hipStream_t stream) {
  const float* x     = (const float*)d_in[0];  // (B,S,IN) = (4,2048,4096) fp32
  const float* sign  = (const float*)d_in[1];  // (OUT,IN) = (4096,4096) fp32, +/-1
  const float* scale = (const float*)d_in[2];  // (4096,)
  const float* bias  = (const float*)d_in[3];  // (4096,)
  float* out = (float*)d_out;                  // (B,S,OUT) fp32

  unsigned short* xb    = (unsigned short*)d_ws;            // M*K bf16 = 64 MiB
  unsigned short* signb = xb + (size_t)M_DIM * K_DIM;       // N*K bf16 = 32 MiB

  // casts: 8 elems/thread
  cvt_f32_bf16_kernel<<<(M_DIM * K_DIM) / 2048, 256, 0, stream>>>(x, xb);
  cvt_f32_bf16_kernel<<<(N_DIM * K_DIM) / 2048, 256, 0, stream>>>(sign, signb);

  // 256x256 tiles: (8192/256) * (4096/256) = 32 * 16 = 512 blocks, 512 thr
  gemm_sign_kernel<<<dim3(512), dim3(512), 0, stream>>>(xb, signb, scale, bias, out);
}

// Round 5
// 507.022 us; speedup vs baseline: 1.1821x; 1.0176x over previous
//
#include <hip/hip_runtime.h>

#define M_DIM 8192
#define N_DIM 4096
#define K_DIM 4096
#define BK 32
#define NT 128   // K_DIM / BK

typedef __attribute__((ext_vector_type(8))) short bf16x8;
typedef __attribute__((ext_vector_type(8))) unsigned short u16x8;
typedef __attribute__((ext_vector_type(16))) float f32x16;

__device__ inline unsigned short f32_to_bf16_rne(float f) {
  unsigned int u = __float_as_uint(f);
  u += 0x7FFFu + ((u >> 16) & 1u);   // round-to-nearest-even
  return (unsigned short)(u >> 16);
}

// fp32 -> bf16 cast, 8 elements/thread, 16B loads + 16B store
__global__ __launch_bounds__(256) void cvt_f32_bf16_kernel(
    const float* __restrict__ in, unsigned short* __restrict__ out) {
  const int i = (blockIdx.x * 256 + threadIdx.x) * 8;
  float4 v0 = *(const float4*)(in + i);
  float4 v1 = *(const float4*)(in + i + 4);
  u16x8 o;
  o[0] = f32_to_bf16_rne(v0.x);
  o[1] = f32_to_bf16_rne(v0.y);
  o[2] = f32_to_bf16_rne(v0.z);
  o[3] = f32_to_bf16_rne(v0.w);
  o[4] = f32_to_bf16_rne(v1.x);
  o[5] = f32_to_bf16_rne(v1.y);
  o[6] = f32_to_bf16_rne(v1.z);
  o[7] = f32_to_bf16_rne(v1.w);
  *(u16x8*)(out + i) = o;
}

// global->LDS 16B DMA, offset ALWAYS 0 (proven form; the builtin's literal
// offset arg produced NaN in round 3).
__device__ inline void gld_lds16(const void* g, void* l) {
  __builtin_amdgcn_global_load_lds(
      (const __attribute__((address_space(1))) void*)(g),
      (__attribute__((address_space(3))) void*)(l), 16, 0, 0);
}

// C[m][n] = sum_k A[m][k] * B[n][k]  (gemm_bt), then *scale[n] + bias[n].
//
// 256x256 tile, BK=32, 256 threads = 4 waves (2M x 2N), wave = 128x128 of C.
// Rationale (round-4 accounting): per CU per K-tile the matrix pipe needs
// 1033 cyc; LDS reads at wave=128x64 were 96KB (~1050-1500 cyc incl
// conflicts) and the lockstep stream serialized the two (measured 2636
// cyc/tile = sum). Wave 128x128 raises FLOP/LDS-byte 42.7 -> 64, cutting
// reads to 64KB/tile/CU (< MFMA floor) at the cost of acc[4][4] f32x16 =
// 256 regs -> 1 wave/SIMD (4 waves/CU, __launch_bounds__(256,1)).
//
// MFMA 32x32x16: A/B frag row = lane&31, k = (lane>>5)*8 + j (k-permutation
// errors cancel between A and B); C/D col = lane&31,
// row = (reg&3)+8*(reg>>2)+4*(lane>>5)  [m74/m101, verified rounds 4].
//
// 4-deep LDS ring, flat 128 KiB: A bufs 0..64K, B 64K..128K. Per K-tile:
// [16 ds_read_b128 | 8 global_load_lds (tile t+3) | vmcnt(16) | s_barrier |
// lgkmcnt(0) | setprio(1) 32 MFMA setprio(0) | s_barrier].  vmcnt(16) =>
// tile t+1 landed, t+2/t+3's 16 loads stay in flight across the barrier.
// Static structure via 4-body unroll (buf indices compile-time).
//
// LDS swizzle (both-sides): 16B chunk of row r stored at chunk ^ p(r),
// p(r) = ((r>>1)&3) ^ ((r>>3)&3); source pre-swizzled (rule #21).
__global__ __launch_bounds__(256, 1) void gemm_sign_kernel(
    const unsigned short* __restrict__ A,
    const unsigned short* __restrict__ Bm,
    const float* __restrict__ scale,
    const float* __restrict__ bias,
    float* __restrict__ C) {
  __shared__ __align__(16) unsigned char sm[131072];  // 128 KiB

  const int tid   = threadIdx.x;
  const int lane  = tid & 63;
  const int wave  = tid >> 6;
  const int waveM = wave >> 1;          // 0..1
  const int waveN = wave & 1;           // 0..1
  const int l31   = lane & 31;
  const int hi    = lane >> 5;          // k-half selector

  // T1: XCD-aware bijective swizzle (512 blocks, 512%8==0).
  const int bid   = blockIdx.x;
  const int wgid  = (bid & 7) * 64 + (bid >> 3);
  const int mBase = (wgid >> 4) * 256;  // 32 M-tiles
  const int nBase = (wgid & 15) * 256;  // 16 N-tiles

  // staging source (pre-swizzled): LDS slot tid -> row = tid>>2 (0..63),
  // storedChunk = tid&3; origChunk = (tid&3) ^ p(row),
  // p(row) = ((tid>>3)&3) ^ ((tid>>5)&3).  Row blocks +64/128/192 keep p
  // (bits 1-4 of row unchanged).
  const int srow = tid >> 2;                                         // 0..63
  const int gcol = ((tid & 3) ^ ((tid >> 3) & 3) ^ ((tid >> 5) & 3)) * 8;
  const unsigned short* aP = A  + (size_t)(mBase + srow) * K_DIM + gcol;
  const unsigned short* bP = Bm + (size_t)(nBase + srow) * K_DIM + gcol;
  const size_t rowStr64 = (size_t)64 * K_DIM;

  // Stage ONE K-tile (8 gloads: 4x64 A-rows, 4x64 B-rows), then advance.
#define STAGE(SBUF) do {                                                  \
    gld_lds16(aP,                 sm + (SBUF)*16384 + tid*16);            \
    gld_lds16(aP +     rowStr64,  sm + (SBUF)*16384 + 4096  + tid*16);    \
    gld_lds16(aP + 2 * rowStr64,  sm + (SBUF)*16384 + 8192  + tid*16);    \
    gld_lds16(aP + 3 * rowStr64,  sm + (SBUF)*16384 + 12288 + tid*16);    \
    gld_lds16(bP,                 sm + 65536 + (SBUF)*16384 + tid*16);    \
    gld_lds16(bP +     rowStr64,  sm + 65536 + (SBUF)*16384 + 4096  + tid*16); \
    gld_lds16(bP + 2 * rowStr64,  sm + 65536 + (SBUF)*16384 + 8192  + tid*16); \
    gld_lds16(bP + 3 * rowStr64,  sm + 65536 + (SBUF)*16384 + 12288 + tid*16); \
    aP += BK; bP += BK;                                                   \
  } while (0)

  // read bases (per-lane, bytes): row bases (waveM*128, waveN*128, mi*32,
  // ni*32) are multiples of 32 => p depends only on l31; chunk = (kk*2+hi)^p.
  const int p = ((l31 >> 1) & 3) ^ ((l31 >> 3) & 3);
  const unsigned char* aRd0 = &sm[(waveM * 128 + l31) * 64 + ((hi ^ p) * 16)];
  const unsigned char* aRd1 = &sm[(waveM * 128 + l31) * 64 + (((2 + hi) ^ p) * 16)];
  const unsigned char* bRd0 = &sm[65536 + (waveN * 128 + l31) * 64 + ((hi ^ p) * 16)];
  const unsigned char* bRd1 = &sm[65536 + (waveN * 128 + l31) * 64 + (((2 + hi) ^ p) * 16)];

  f32x16 acc[4][4];
#pragma unroll
  for (int i = 0; i < 4; ++i)
#pragma unroll
    for (int j = 0; j < 4; ++j)
#pragma unroll
      for (int r = 0; r < 16; ++r)
        acc[i][j][r] = 0.f;

  // BODY(BUF, DO_STAGE, SBUF, VMODE): compute ring buf BUF; optionally stage
  // next tile into SBUF. VMODE: 0 none, 1 vmcnt(16), 2 vmcnt(0) (tail only).
#define BODY(BUF, DO_STAGE, SBUF, VMODE)                                \
  {                                                                     \
    bf16x8 af[4][2], bf[4][2];                                          \
    _Pragma("unroll")                                                   \
    for (int mi = 0; mi < 4; ++mi) {                                    \
      af[mi][0] = *(const bf16x8*)(aRd0 + (BUF) * 16384 + mi * 2048);   \
      af[mi][1] = *(const bf16x8*)(aRd1 + (BUF) * 16384 + mi * 2048);   \
    }                                                                   \
    _Pragma("unroll")                                                   \
    for (int ni = 0; ni < 4; ++ni) {                                    \
      bf[ni][0] = *(const bf16x8*)(bRd0 + (BUF) * 16384 + ni * 2048);   \
      bf[ni][1] = *(const bf16x8*)(bRd1 + (BUF) * 16384 + ni * 2048);   \
    }                                                                   \
    if (DO_STAGE) STAGE(SBUF);                                          \
    if ((VMODE) == 1) asm volatile("s_waitcnt vmcnt(16)" ::: "memory"); \
    if ((VMODE) == 2) asm volatile("s_waitcnt vmcnt(0)" ::: "memory");  \
    __builtin_amdgcn_s_barrier();                                       \
    asm volatile("s_waitcnt lgkmcnt(0)" ::: "memory");                  \
    __builtin_amdgcn_s_setprio(1);                                      \
    _Pragma("unroll")                                                   \
    for (int mi = 0; mi < 4; ++mi)                                      \
      _Pragma("unroll")                                                 \
      for (int ni = 0; ni < 4; ++ni) {                                  \
        acc[mi][ni] = __builtin_amdgcn_mfma_f32_32x32x16_bf16(          \
            af[mi][0], bf[ni][0], acc[mi][ni], 0, 0, 0);                \
        acc[mi][ni] = __builtin_amdgcn_mfma_f32_32x32x16_bf16(          \
            af[mi][1], bf[ni][1], acc[mi][ni], 0, 0, 0);                \
      }                                                                 \
    __builtin_amdgcn_s_setprio(0);                                      \
    __builtin_amdgcn_s_barrier();                                       \
  }

  // prologue: stage tiles 0,1,2 (24 loads); vmcnt(16) => tile 0 landed,
  // tiles 1,2 flying; barrier publishes staging before first reads.
  STAGE(0); STAGE(1); STAGE(2);   // aP/bP now at tile 3
  asm volatile("s_waitcnt vmcnt(16)" ::: "memory");
  __builtin_amdgcn_s_barrier();

  // main loop: 31 iters x 4 tiles = tiles 0..123, staging tiles 3..126.
  // In-body vmcnt(16) (24 outstanding, wait oldest 8) => tile t+1 landed
  // before the barrier that precedes iteration t+1's reads. Buf overwrite
  // (t+3 into buf (t-1)&3) is issued only after the end-barrier of the body
  // that last read it.
  for (int it = 0; it < 31; ++it) {
    BODY(0, 1, 3, 1);
    BODY(1, 1, 0, 1);
    BODY(2, 1, 1, 1);
    BODY(3, 1, 2, 1);
  }

  // tail: tiles 124..127. 124 stages tile 127; vmcnt(16) => 125 landed;
  // 125: vmcnt(0) => 126,127 landed; 126,127: no waits needed.
  BODY(0, 1, 3, 1);
  BODY(1, 0, 0, 2);
  BODY(2, 0, 0, 0);
  BODY(3, 0, 0, 0);

#undef BODY
#undef STAGE

  // epilogue: 32x32 C/D layout: col = lane&31, row = (reg&3)+8*(reg>>2)+4*hi
#pragma unroll
  for (int ni = 0; ni < 4; ++ni) {
    const int c = nBase + waveN * 128 + ni * 32 + l31;
    const float sc = scale[c];
    const float bs = bias[c];
#pragma unroll
    for (int mi = 0; mi < 4; ++mi) {
      const int r0 = mBase + waveM * 128 + mi * 32 + 4 * hi;
#pragma unroll
      for (int r = 0; r < 16; ++r) {
        const int row = r0 + (r & 3) + 8 * (r >> 2);
        C[(size_t)row * N_DIM + c] = acc[mi][ni][r] * sc + bs;
      }
    }
  }
}

extern "C" void kernel_launch(void* const* d_in, const int* in_sizes, int n_in,
                              void* d_out, int out_size, void* d_ws, size_t ws_size,
                              hipStream_t stream) {
  const float* x     = (const float*)d_in[0];  // (B,S,IN) = (4,2048,4096) fp32
  const float* sign  = (const float*)d_in[1];  // (OUT,IN) = (4096,4096) fp32, +/-1
  const float* scale = (const float*)d_in[2];  // (4096,)
  const float* bias  = (const float*)d_in[3];  // (4096,)
  float* out = (float*)d_out;                  // (B,S,OUT) fp32

  unsigned short* xb    = (unsigned short*)d_ws;            // M*K bf16 = 64 MiB
  unsigned short* signb = xb + (size_t)M_DIM * K_DIM;       // N*K bf16 = 32 MiB

  // casts: 8 elems/thread
  cvt_f32_bf16_kernel<<<(M_DIM * K_DIM) / 2048, 256, 0, stream>>>(x, xb);
  cvt_f32_bf16_kernel<<<(N_DIM * K_DIM) / 2048, 256, 0, stream>>>(sign, signb);

  // 256x256 tiles: (8192/256) * (4096/256) = 32 * 16 = 512 blocks, 256 thr
  gemm_sign_kernel<<<dim3(512), dim3(256), 0, stream>>>(xb, signb, scale, bias, out);
}

// Round 6
// 494.165 us; speedup vs baseline: 1.2128x; 1.0260x over previous
//
#include <hip/hip_runtime.h>

#define M_DIM 8192
#define N_DIM 4096
#define K_DIM 4096
#define BK 32
#define NT 128   // K_DIM / BK

typedef __attribute__((ext_vector_type(8))) short bf16x8;
typedef __attribute__((ext_vector_type(8))) unsigned short u16x8;
typedef __attribute__((ext_vector_type(16))) float f32x16;

__device__ inline unsigned short f32_to_bf16_rne(float f) {
  unsigned int u = __float_as_uint(f);
  u += 0x7FFFu + ((u >> 16) & 1u);   // round-to-nearest-even
  return (unsigned short)(u >> 16);
}

// fp32 -> bf16 cast, 8 elements/thread, 16B loads + 16B store
__global__ __launch_bounds__(256) void cvt_f32_bf16_kernel(
    const float* __restrict__ in, unsigned short* __restrict__ out) {
  const int i = (blockIdx.x * 256 + threadIdx.x) * 8;
  float4 v0 = *(const float4*)(in + i);
  float4 v1 = *(const float4*)(in + i + 4);
  u16x8 o;
  o[0] = f32_to_bf16_rne(v0.x);
  o[1] = f32_to_bf16_rne(v0.y);
  o[2] = f32_to_bf16_rne(v0.z);
  o[3] = f32_to_bf16_rne(v0.w);
  o[4] = f32_to_bf16_rne(v1.x);
  o[5] = f32_to_bf16_rne(v1.y);
  o[6] = f32_to_bf16_rne(v1.z);
  o[7] = f32_to_bf16_rne(v1.w);
  *(u16x8*)(out + i) = o;
}

// global->LDS 16B DMA, offset ALWAYS 0 (proven form; round-3's literal
// offset arg produced NaN).
__device__ inline void gld_lds16(const void* g, void* l) {
  __builtin_amdgcn_global_load_lds(
      (const __attribute__((address_space(1))) void*)(g),
      (__attribute__((address_space(3))) void*)(l), 16, 0, 0);
}

// C[m][n] = sum_k A[m][k] * B[n][k]  (gemm_bt), then *scale[n] + bias[n].
//
// 256x256 tile, BK=32, 512 threads = 8 waves (2M x 4N), wave = 128x64 of C.
// PHASE-SPLIT schedule (T3, m201 pattern): rounds 2/4/5 all measured
// ~2550-2640 cyc/tile (MFMA floor 1033) because the single-phase lockstep
// [all reads | lgkm(0) | all MFMA] serializes the LDS and matrix pipes.
// Now 2 phases per K-tile, 2 waves/SIMD for TLP:
//   ph1: 8 ds_read (af[0..1][k], bf[*][k]) | STAGE_A(t+3) | barrier |
//        lgkm(0) | setprio(1) 8 MFMA (acc[0..1][*]) setprio(0) | barrier
//   ph2: 4 ds_read (af[2..3][k])           | STAGE_B(t+3) | vmcnt(8) |
//        barrier | lgkm(0) | setprio(1) 8 MFMA (acc[2..3][*]) | barrier
// One wave's MFMA window overlaps the sibling wave's read/stage window.
// vmcnt(8): outstanding = tiles t+2,t+3 (4 gloads each); everything older
// (incl. t+1, read next tile) retired. Never vmcnt(0) in the main loop.
//
// MFMA 32x32x16 (ceiling 2495 TF): A/B frag row = lane&31, k = hi*8+j
// (k-permutation errors cancel between A and B); C/D col = lane&31,
// row = (reg&3)+8*(reg>>2)+4*hi  [m74/m101, HW-verified rounds 4-5].
//
// 4-deep LDS ring, flat 128 KiB: A bufs 0..64K, B 64K..128K; static buf
// indices via 4-body unroll. Hazard chain as rounds 4-5 (verified): buf
// overwrite (t+3 -> buf (t-1)&3) issues only after the barrier closing the
// body that last read it; every wave's own staging for tile t retires at
// its t-1 vmcnt(8), published by the following barrier.
//
// LDS swizzle (both-sides): 16B chunk of row r stored at chunk ^ p(r),
// p(r) = ((r>>1)&3) ^ ((r>>3)&3); source pre-swizzled (rule #21).
__global__ __launch_bounds__(512, 2) void gemm_sign_kernel(
    const unsigned short* __restrict__ A,
    const unsigned short* __restrict__ Bm,
    const float* __restrict__ scale,
    const float* __restrict__ bias,
    float* __restrict__ C) {
  __shared__ __align__(16) unsigned char sm[131072];  // 128 KiB

  const int tid   = threadIdx.x;
  const int lane  = tid & 63;
  const int wave  = tid >> 6;
  const int waveM = wave >> 2;          // 0..1
  const int waveN = wave & 3;           // 0..3
  const int l31   = lane & 31;
  const int hi    = lane >> 5;          // k-half selector

  // T1: XCD-aware bijective swizzle (512 blocks, 512%8==0).
  const int bid   = blockIdx.x;
  const int wgid  = (bid & 7) * 64 + (bid >> 3);
  const int mBase = (wgid >> 4) * 256;  // 32 M-tiles
  const int nBase = (wgid & 15) * 256;  // 16 N-tiles

  // staging source (pre-swizzled): LDS slot tid -> row = tid>>2 (0..127),
  // storedChunk = tid&3; origChunk = (tid&3) ^ p(row),
  // p(row) = ((tid>>3)&3) ^ ((tid>>5)&3).  Rows +128 keep p.
  const int srow = tid >> 2;                                         // 0..127
  const int gcol = ((tid & 3) ^ ((tid >> 3) & 3) ^ ((tid >> 5) & 3)) * 8;
  const unsigned short* aP = A  + (size_t)(mBase + srow) * K_DIM + gcol;
  const unsigned short* bP = Bm + (size_t)(nBase + srow) * K_DIM + gcol;
  const size_t rowStr128 = (size_t)128 * K_DIM;

  // A-half / B-half of one K-tile: 2 gloads each (512 thr x 16 B = 8 KB).
#define STAGE_A(SBUF) do {                                              \
    gld_lds16(aP,             sm + (SBUF)*16384 + tid*16);              \
    gld_lds16(aP + rowStr128, sm + (SBUF)*16384 + 8192 + tid*16);       \
    aP += BK;                                                           \
  } while (0)
#define STAGE_B(SBUF) do {                                              \
    gld_lds16(bP,             sm + 65536 + (SBUF)*16384 + tid*16);      \
    gld_lds16(bP + rowStr128, sm + 65536 + (SBUF)*16384 + 8192 + tid*16); \
    bP += BK;                                                           \
  } while (0)

  // read bases (per-lane, bytes): row bases (waveM*128, waveN*64, mi*32,
  // ni*32) are multiples of 32 => p depends only on l31; chunk = (kk*2+hi)^p.
  const int p = ((l31 >> 1) & 3) ^ ((l31 >> 3) & 3);
  const unsigned char* aRd0 = &sm[(waveM * 128 + l31) * 64 + ((hi ^ p) * 16)];
  const unsigned char* aRd1 = &sm[(waveM * 128 + l31) * 64 + (((2 + hi) ^ p) * 16)];
  const unsigned char* bRd0 = &sm[65536 + (waveN * 64 + l31) * 64 + ((hi ^ p) * 16)];
  const unsigned char* bRd1 = &sm[65536 + (waveN * 64 + l31) * 64 + (((2 + hi) ^ p) * 16)];

  f32x16 acc[4][2];
#pragma unroll
  for (int i = 0; i < 4; ++i)
#pragma unroll
    for (int j = 0; j < 2; ++j)
#pragma unroll
      for (int r = 0; r < 16; ++r)
        acc[i][j][r] = 0.f;

  // BODY(BUF, DO_STAGE, VMODE): one K-tile from ring buf BUF, 2 phases.
  // VMODE: 0 none, 1 vmcnt(8), 2 vmcnt(0) (tail only).
#define BODY(BUF, DO_STAGE, VMODE)                                      \
  {                                                                     \
    bf16x8 bf[2][2];                                                    \
    {                                                                   \
      bf16x8 af[2][2];                                                  \
      _Pragma("unroll")                                                 \
      for (int mi = 0; mi < 2; ++mi) {                                  \
        af[mi][0] = *(const bf16x8*)(aRd0 + (BUF) * 16384 + mi * 2048); \
        af[mi][1] = *(const bf16x8*)(aRd1 + (BUF) * 16384 + mi * 2048); \
      }                                                                 \
      _Pragma("unroll")                                                 \
      for (int ni = 0; ni < 2; ++ni) {                                  \
        bf[ni][0] = *(const bf16x8*)(bRd0 + (BUF) * 16384 + ni * 2048); \
        bf[ni][1] = *(const bf16x8*)(bRd1 + (BUF) * 16384 + ni * 2048); \
      }                                                                 \
      if (DO_STAGE) STAGE_A((BUF + 3) & 3);                             \
      __builtin_amdgcn_s_barrier();                                     \
      asm volatile("s_waitcnt lgkmcnt(0)" ::: "memory");                \
      __builtin_amdgcn_s_setprio(1);                                    \
      _Pragma("unroll")                                                 \
      for (int mi = 0; mi < 2; ++mi)                                    \
        _Pragma("unroll")                                               \
        for (int ni = 0; ni < 2; ++ni) {                                \
          acc[mi][ni] = __builtin_amdgcn_mfma_f32_32x32x16_bf16(        \
              af[mi][0], bf[ni][0], acc[mi][ni], 0, 0, 0);              \
          acc[mi][ni] = __builtin_amdgcn_mfma_f32_32x32x16_bf16(        \
              af[mi][1], bf[ni][1], acc[mi][ni], 0, 0, 0);              \
        }                                                               \
      __builtin_amdgcn_s_setprio(0);                                    \
      __builtin_amdgcn_s_barrier();                                     \
    }                                                                   \
    {                                                                   \
      bf16x8 af[2][2];                                                  \
      _Pragma("unroll")                                                 \
      for (int mi = 0; mi < 2; ++mi) {                                  \
        af[mi][0] = *(const bf16x8*)(aRd0 + (BUF) * 16384 + (2 + mi) * 2048); \
        af[mi][1] = *(const bf16x8*)(aRd1 + (BUF) * 16384 + (2 + mi) * 2048); \
      }                                                                 \
      if (DO_STAGE) STAGE_B((BUF + 3) & 3);                             \
      if ((VMODE) == 1) asm volatile("s_waitcnt vmcnt(8)" ::: "memory"); \
      if ((VMODE) == 2) asm volatile("s_waitcnt vmcnt(0)" ::: "memory"); \
      __builtin_amdgcn_s_barrier();                                     \
      asm volatile("s_waitcnt lgkmcnt(0)" ::: "memory");                \
      __builtin_amdgcn_s_setprio(1);                                    \
      _Pragma("unroll")                                                 \
      for (int mi = 0; mi < 2; ++mi)                                    \
        _Pragma("unroll")                                               \
        for (int ni = 0; ni < 2; ++ni) {                                \
          acc[2 + mi][ni] = __builtin_amdgcn_mfma_f32_32x32x16_bf16(    \
              af[mi][0], bf[ni][0], acc[2 + mi][ni], 0, 0, 0);          \
          acc[2 + mi][ni] = __builtin_amdgcn_mfma_f32_32x32x16_bf16(    \
              af[mi][1], bf[ni][1], acc[2 + mi][ni], 0, 0, 0);          \
        }                                                               \
      __builtin_amdgcn_s_setprio(0);                                    \
      __builtin_amdgcn_s_barrier();                                     \
    }                                                                   \
  }

  // prologue: stage tiles 0,1,2 (12 gloads); vmcnt(8) => tile 0 landed,
  // tiles 1,2 flying; barrier publishes staging before first reads.
  STAGE_A(0); STAGE_B(0);
  STAGE_A(1); STAGE_B(1);
  STAGE_A(2); STAGE_B(2);   // aP/bP now at tile 3
  asm volatile("s_waitcnt vmcnt(8)" ::: "memory");
  __builtin_amdgcn_s_barrier();

  // main loop: 31 iters x 4 tiles = tiles 0..123, staging tiles 3..126.
  for (int it = 0; it < 31; ++it) {
    BODY(0, 1, 1);
    BODY(1, 1, 1);
    BODY(2, 1, 1);
    BODY(3, 1, 1);
  }

  // tail: tiles 124..127. 124 stages tile 127, vmcnt(8) => 125 landed;
  // 125: vmcnt(0) => 126,127 landed; 126,127: no waits needed.
  BODY(0, 1, 1);
  BODY(1, 0, 2);
  BODY(2, 0, 0);
  BODY(3, 0, 0);

#undef BODY
#undef STAGE_A
#undef STAGE_B

  // epilogue: 32x32 C/D layout: col = lane&31, row = (reg&3)+8*(reg>>2)+4*hi
#pragma unroll
  for (int ni = 0; ni < 2; ++ni) {
    const int c = nBase + waveN * 64 + ni * 32 + l31;
    const float sc = scale[c];
    const float bs = bias[c];
#pragma unroll
    for (int mi = 0; mi < 4; ++mi) {
      const int r0 = mBase + waveM * 128 + mi * 32 + 4 * hi;
#pragma unroll
      for (int r = 0; r < 16; ++r) {
        const int row = r0 + (r & 3) + 8 * (r >> 2);
        C[(size_t)row * N_DIM + c] = acc[mi][ni][r] * sc + bs;
      }
    }
  }
}

extern "C" void kernel_launch(void* const* d_in, const int* in_sizes, int n_in,
                              void* d_out, int out_size, void* d_ws, size_t ws_size,
                              hipStream_t stream) {
  const float* x     = (const float*)d_in[0];  // (B,S,IN) = (4,2048,4096) fp32
  const float* sign  = (const float*)d_in[1];  // (OUT,IN) = (4096,4096) fp32, +/-1
  const float* scale = (const float*)d_in[2];  // (4096,)
  const float* bias  = (const float*)d_in[3];  // (4096,)
  float* out = (float*)d_out;                  // (B,S,OUT) fp32

  unsigned short* xb    = (unsigned short*)d_ws;            // M*K bf16 = 64 MiB
  unsigned short* signb = xb + (size_t)M_DIM * K_DIM;       // N*K bf16 = 32 MiB

  // casts: 8 elems/thread
  cvt_f32_bf16_kernel<<<(M_DIM * K_DIM) / 2048, 256, 0, stream>>>(x, xb);
  cvt_f32_bf16_kernel<<<(N_DIM * K_DIM) / 2048, 256, 0, stream>>>(sign, signb);

  // 256x256 tiles: (8192/256) * (4096/256) = 32 * 16 = 512 blocks, 512 thr
  gemm_sign_kernel<<<dim3(512), dim3(512), 0, stream>>>(xb, signb, scale, bias, out);
}